// Round 13
// baseline (900.667 us; speedup 1.0000x reference)
//
#include <hip/hip_runtime.h>

// MPNN on MI355X.
//
// Algebra: msg layer-1 is linear before its relu:
//   m1 = relu(P[dst] + Q[src] + ea@W1e + b1), P = h@W1[0:64]+b1, Q = h@W1[64:128]
// R3: m2 GEMM via bf16 MFMA (A plain bf16 = random rounding, W hi+lo bf16).
// R4: dst-sorted CSR, consumer-side aggregation (killed 51M fp32 atomics).
// R5-R7: flat edge batches, metadata vector load + v_readlane, ballot
//     segment mask, per-segment coalesced atomic; node GEMMs MFMA-ized.
// R8/R10 (REVERTED): restructuring the staging loop defeats compiler load
//     pipelining. Keep it straight-line.
// R9: P/Q stored bf16. R12: fragment-layout prepped hi/lo weights (-60us on
//     node GEMMs); contiguous chunks (neutral).
// R13: k_edge batches 32 -> 64 edges/wave: halves per-batch fixed costs and
//     drain points, 128 gathers in flight per drain, full-wave metadata
//     (64-bit ballot, no lane dup). LDS 37KB/block, grid 1024 = exactly
//     4 blocks/CU resident. Node grids 1 tile/wave (NB_T 782).

typedef __attribute__((ext_vector_type(8))) short short8;
typedef __attribute__((ext_vector_type(4))) float float4v;

__device__ __forceinline__ unsigned short f2bf(float f) {
    unsigned int u = __float_as_uint(f);
    unsigned int r = u + 0x7fff + ((u >> 16) & 1);   // RTNE
    return (unsigned short)(r >> 16);
}
__device__ __forceinline__ float bf2f(unsigned short u) {
    return __uint_as_float(((unsigned int)u) << 16);
}

#define MFMA16(a, b, c) __builtin_amdgcn_mfma_f32_16x16x32_bf16(a, b, c, 0, 0, 0)

struct bfpair { short hi, lo; };
__device__ __forceinline__ bfpair wsplit(float wv) {
    bfpair p;
    unsigned short h = f2bf(wv);
    float hf = __uint_as_float(((unsigned int)h) << 16);
    p.hi = (short)h;
    p.lo = (short)f2bf(wv - hf);
    return p;
}

// fragment-layout weight prep offsets (ushort elements)
#define WP_TOTAL 106496
#define OFF_IN   0
#define OFF_PRE(l)  (8192  + (l) * 8192)
#define OFF_MW2(l)  (40960 + (l) * 4096)
#define OFF_UW1(l)  (57344 + (l) * 8192)
#define OFF_UW2(l)  (90112 + (l) * 4096)

// ---------------- weight prep: fp32 -> hi/lo bf16 in fragment layout ----------------
__global__ __launch_bounds__(256) void k_wprep(const float* __restrict__ lin_w,
        const float* __restrict__ mw1, const float* __restrict__ mw2,
        const float* __restrict__ uw1, const float* __restrict__ uw2,
        unsigned short* __restrict__ H, unsigned short* __restrict__ L) {
    const int tid = blockIdx.x * 256 + threadIdx.x;
    if (tid >= WP_TOTAL) return;
    float val;
    if (tid < 8192) {                                  // lin_in_w: KF=4, NT=4
        int rem = tid;
        int nt = rem >> 11, kf = (rem >> 9) & 3;
        int lane = (rem >> 3) & 63, j = rem & 7;
        int k = kf * 32 + (lane >> 4) * 8 + j;
        val = lin_w[k * 64 + nt * 16 + (lane & 15)];
    } else if (tid < 40960) {                          // msg_w1[0:128]: KF=2, NT=8
        int t = tid - 8192, layer = t >> 13, rem = t & 8191;
        int nt = rem >> 10, kf = (rem >> 9) & 1;
        int lane = (rem >> 3) & 63, j = rem & 7;
        int k = kf * 32 + (lane >> 4) * 8 + j;
        const float* w1 = mw1 + (size_t)layer * 134 * 64;
        val = (nt < 4) ? w1[k * 64 + nt * 16 + (lane & 15)]
                       : w1[(64 + k) * 64 + (nt - 4) * 16 + (lane & 15)];
    } else if (tid < 57344) {                          // msg_w2: KF=2, NT=4
        int t = tid - 40960, layer = t >> 12, rem = t & 4095;
        int nt = rem >> 10, kf = (rem >> 9) & 1;
        int lane = (rem >> 3) & 63, j = rem & 7;
        int k = kf * 32 + (lane >> 4) * 8 + j;
        val = mw2[(size_t)layer * 4096 + k * 64 + nt * 16 + (lane & 15)];
    } else if (tid < 90112) {                          // upd_w1: KF=4, NT=4
        int t = tid - 57344, layer = t >> 13, rem = t & 8191;
        int nt = rem >> 11, kf = (rem >> 9) & 3;
        int lane = (rem >> 3) & 63, j = rem & 7;
        int k = kf * 32 + (lane >> 4) * 8 + j;
        val = uw1[(size_t)layer * 8192 + k * 64 + nt * 16 + (lane & 15)];
    } else {                                           // upd_w2: KF=2, NT=4
        int t = tid - 90112, layer = t >> 12, rem = t & 4095;
        int nt = rem >> 10, kf = (rem >> 9) & 1;
        int lane = (rem >> 3) & 63, j = rem & 7;
        int k = kf * 32 + (lane >> 4) * 8 + j;
        val = uw2[(size_t)layer * 4096 + k * 64 + nt * 16 + (lane & 15)];
    }
    bfpair p = wsplit(val);
    H[tid] = (unsigned short)p.hi;
    L[tid] = (unsigned short)p.lo;
}

#define LOADFRAG(dst, arr, nt, KF, kf) \
    dst = *(const short8*)&arr[((((nt) * (KF)) + (kf)) * 64 + lane) * 8]

// ---------------- CSR build ----------------
__global__ __launch_bounds__(256) void k_hist(const int* __restrict__ dst,
        int* __restrict__ deg, int nEdges) {
    int e = blockIdx.x * blockDim.x + threadIdx.x;
    if (e < nEdges) atomicAdd(&deg[dst[e]], 1);
}

__global__ __launch_bounds__(256) void k_scan1(const int* __restrict__ deg,
        int* __restrict__ local, int* __restrict__ bsum, int nNodes) {
    __shared__ int sm[256];
    const int t = threadIdx.x;
    const int n = blockIdx.x * 256 + t;
    int v = (n < nNodes) ? deg[n] : 0;
    sm[t] = v;
    __syncthreads();
    for (int off = 1; off < 256; off <<= 1) {
        int u = (t >= off) ? sm[t - off] : 0;
        __syncthreads();
        sm[t] += u;
        __syncthreads();
    }
    if (n < nNodes) local[n] = sm[t] - v;
    if (t == 255) bsum[blockIdx.x] = sm[255];
}

__global__ __launch_bounds__(256) void k_scan2(int* __restrict__ bsum, int nB) {
    __shared__ int sm[256];
    const int t = threadIdx.x;
    int v = (t < nB) ? bsum[t] : 0;
    sm[t] = v;
    __syncthreads();
    for (int off = 1; off < 256; off <<= 1) {
        int u = (t >= off) ? sm[t - off] : 0;
        __syncthreads();
        sm[t] += u;
        __syncthreads();
    }
    if (t < nB) bsum[t] = sm[t] - v;
}

__global__ __launch_bounds__(256) void k_scan3(const int* __restrict__ local,
        const int* __restrict__ bsum, int* __restrict__ cursor, int nNodes) {
    int n = blockIdx.x * 256 + threadIdx.x;
    if (n < nNodes) cursor[n] = bsum[blockIdx.x] + local[n];
}

__global__ __launch_bounds__(256) void k_scatter(const int* __restrict__ src,
        const int* __restrict__ dst, const float* __restrict__ ea,
        int* __restrict__ cursor, int* __restrict__ col_src,
        int* __restrict__ dst_s, float* __restrict__ ea_s, int nEdges) {
    int e = blockIdx.x * blockDim.x + threadIdx.x;
    if (e < nEdges) {
        int d = dst[e];
        int pos = atomicAdd(&cursor[d], 1);
        col_src[pos] = src[e];
        dst_s[pos] = d;
        const float* p = ea + (size_t)e * 6;
        float* q = ea_s + (size_t)pos * 6;
#pragma unroll
        for (int j = 0; j < 6; ++j) q[j] = p[j];
    }
}

// ---------------- node-side MFMA GEMM kernels ----------------
// A-frag: A[m=col][k=quad*8+j]; C: col=lane&15, row=quad*4+reg (verified).

// h = x @ Win + b   (K=128, N=64)
__global__ __launch_bounds__(256) void k_in(const float* __restrict__ x,
        const unsigned short* __restrict__ wh, const unsigned short* __restrict__ wl,
        const float* __restrict__ bia, float* __restrict__ h, int nNodes) {
    const int lane = threadIdx.x & 63;
    const int wib  = threadIdx.x >> 6;
    const int quad = lane >> 4, col = lane & 15;
    __shared__ unsigned short sm[4][16 * 136];
    unsigned short* __restrict__ mt = sm[wib];

    short8 bh[4][4], bl[4][4];
#pragma unroll
    for (int nt = 0; nt < 4; ++nt)
#pragma unroll
        for (int kf = 0; kf < 4; ++kf) {
            LOADFRAG(bh[nt][kf], wh, nt, 4, kf);
            LOADFRAG(bl[nt][kf], wl, nt, 4, kf);
        }
    float bv[4];
#pragma unroll
    for (int nt = 0; nt < 4; ++nt) bv[nt] = bia[nt * 16 + col];

    const int nTiles = (nNodes + 15) >> 4;
    const int wid = blockIdx.x * 4 + wib;
    const int nw  = gridDim.x * 4;
    for (int tile = wid; tile < nTiles; tile += nw) {
        const int base = tile * 16;
#pragma unroll
        for (int j = 0; j < 16; ++j) {
            int row = min(base + j, nNodes - 1);
            mt[j * 136 + lane]      = f2bf(x[(size_t)row * 128 + lane]);
            mt[j * 136 + 64 + lane] = f2bf(x[(size_t)row * 128 + 64 + lane]);
        }
        __builtin_amdgcn_s_waitcnt(0);
        short8 a[4];
#pragma unroll
        for (int kf = 0; kf < 4; ++kf)
            a[kf] = *(const short8*)&mt[col * 136 + kf * 32 + quad * 8];
#pragma unroll
        for (int nt = 0; nt < 4; ++nt) {
            float4v c = {0.f, 0.f, 0.f, 0.f};
#pragma unroll
            for (int kf = 0; kf < 4; ++kf) c = MFMA16(a[kf], bh[nt][kf], c);
#pragma unroll
            for (int kf = 0; kf < 4; ++kf) c = MFMA16(a[kf], bl[nt][kf], c);
#pragma unroll
            for (int r = 0; r < 4; ++r) {
                int row = base + quad * 4 + r;
                if (row < nNodes)
                    h[(size_t)row * 64 + nt * 16 + col] = c[r] + bv[nt];
            }
        }
    }
}

// [P|Q] = h @ [W1[0:64] | W1[64:128]]; P += b1   (K=64, N=128), bf16 outputs
__global__ __launch_bounds__(256) void k_pre(const float* __restrict__ h,
        const unsigned short* __restrict__ wh, const unsigned short* __restrict__ wl,
        const float* __restrict__ b1m,
        unsigned short* __restrict__ P, unsigned short* __restrict__ Q,
        int nNodes) {
    const int lane = threadIdx.x & 63;
    const int wib  = threadIdx.x >> 6;
    const int quad = lane >> 4, col = lane & 15;
    __shared__ unsigned short sm[4][16 * 72];
    unsigned short* __restrict__ mt = sm[wib];

    short8 bh[8][2], bl[8][2];
#pragma unroll
    for (int nt = 0; nt < 8; ++nt)
#pragma unroll
        for (int kf = 0; kf < 2; ++kf) {
            LOADFRAG(bh[nt][kf], wh, nt, 2, kf);
            LOADFRAG(bl[nt][kf], wl, nt, 2, kf);
        }
    float bv1[4];
#pragma unroll
    for (int nt = 0; nt < 4; ++nt) bv1[nt] = b1m[nt * 16 + col];

    const int nTiles = (nNodes + 15) >> 4;
    const int wid = blockIdx.x * 4 + wib;
    const int nw  = gridDim.x * 4;
    for (int tile = wid; tile < nTiles; tile += nw) {
        const int base = tile * 16;
#pragma unroll
        for (int j = 0; j < 16; ++j) {
            int row = min(base + j, nNodes - 1);
            mt[j * 72 + lane] = f2bf(h[(size_t)row * 64 + lane]);
        }
        __builtin_amdgcn_s_waitcnt(0);
        short8 a0 = *(const short8*)&mt[col * 72 + quad * 8];
        short8 a1 = *(const short8*)&mt[col * 72 + 32 + quad * 8];
#pragma unroll
        for (int nt = 0; nt < 8; ++nt) {
            float4v c = {0.f, 0.f, 0.f, 0.f};
            c = MFMA16(a0, bh[nt][0], c);
            c = MFMA16(a1, bh[nt][1], c);
            c = MFMA16(a0, bl[nt][0], c);
            c = MFMA16(a1, bl[nt][1], c);
            unsigned short* __restrict__ outp = (nt < 4) ? P : Q;
            const int nc = (nt & 3) * 16 + col;
            const float badd = (nt < 4) ? bv1[nt & 3] : 0.f;
#pragma unroll
            for (int r = 0; r < 4; ++r) {
                int row = base + quad * 4 + r;
                if (row < nNodes) outp[(size_t)row * 64 + nc] = f2bf(c[r] + badd);
            }
        }
    }
}

// tv = relu([h|agg] @ U1 + b1)   (K=128, N=64); tv aliases agg (in-place)
__global__ __launch_bounds__(256) void k_upd1(const float* __restrict__ h,
        const float* __restrict__ agg,
        const unsigned short* __restrict__ wh, const unsigned short* __restrict__ wl,
        const float* __restrict__ b1, float* __restrict__ tv, int nNodes) {
    const int lane = threadIdx.x & 63;
    const int wib  = threadIdx.x >> 6;
    const int quad = lane >> 4, col = lane & 15;
    __shared__ unsigned short sm[4][16 * 136];
    unsigned short* __restrict__ mt = sm[wib];

    short8 bh[4][4], bl[4][4];
#pragma unroll
    for (int nt = 0; nt < 4; ++nt)
#pragma unroll
        for (int kf = 0; kf < 4; ++kf) {
            LOADFRAG(bh[nt][kf], wh, nt, 4, kf);
            LOADFRAG(bl[nt][kf], wl, nt, 4, kf);
        }
    float bv[4];
#pragma unroll
    for (int nt = 0; nt < 4; ++nt) bv[nt] = b1[nt * 16 + col];

    const int nTiles = (nNodes + 15) >> 4;
    const int wid = blockIdx.x * 4 + wib;
    const int nw  = gridDim.x * 4;
    for (int tile = wid; tile < nTiles; tile += nw) {
        const int base = tile * 16;
#pragma unroll
        for (int j = 0; j < 16; ++j) {
            int row = min(base + j, nNodes - 1);
            mt[j * 136 + lane]      = f2bf(h[(size_t)row * 64 + lane]);
            mt[j * 136 + 64 + lane] = f2bf(agg[(size_t)row * 64 + lane]);
        }
        __builtin_amdgcn_s_waitcnt(0);
        short8 a[4];
#pragma unroll
        for (int kf = 0; kf < 4; ++kf)
            a[kf] = *(const short8*)&mt[col * 136 + kf * 32 + quad * 8];
#pragma unroll
        for (int nt = 0; nt < 4; ++nt) {
            float4v c = {0.f, 0.f, 0.f, 0.f};
#pragma unroll
            for (int kf = 0; kf < 4; ++kf) c = MFMA16(a[kf], bh[nt][kf], c);
#pragma unroll
            for (int kf = 0; kf < 4; ++kf) c = MFMA16(a[kf], bl[nt][kf], c);
#pragma unroll
            for (int r = 0; r < 4; ++r) {
                int row = base + quad * 4 + r;
                if (row < nNodes)
                    tv[(size_t)row * 64 + nt * 16 + col] = fmaxf(c[r] + bv[nt], 0.f);
            }
        }
    }
}

// h += relu(tv @ U2 + b2); zero tv(=agg) for next layer; optional colsum
__global__ __launch_bounds__(256) void k_upd2(float* __restrict__ h,
        float* __restrict__ tv,
        const unsigned short* __restrict__ wh, const unsigned short* __restrict__ wl,
        const float* __restrict__ b2, float* __restrict__ colsum,
        int nNodes, int doCS) {
    const int lane = threadIdx.x & 63;
    const int wib  = threadIdx.x >> 6;
    const int quad = lane >> 4, col = lane & 15;
    __shared__ unsigned short sm[4][16 * 72];
    unsigned short* __restrict__ mt = sm[wib];

    short8 bh[4][2], bl[4][2];
#pragma unroll
    for (int nt = 0; nt < 4; ++nt)
#pragma unroll
        for (int kf = 0; kf < 2; ++kf) {
            LOADFRAG(bh[nt][kf], wh, nt, 2, kf);
            LOADFRAG(bl[nt][kf], wl, nt, 2, kf);
        }
    float bv[4];
#pragma unroll
    for (int nt = 0; nt < 4; ++nt) bv[nt] = b2[nt * 16 + col];

    float cs0 = 0.f, cs1 = 0.f, cs2 = 0.f, cs3 = 0.f;
    const int nTiles = (nNodes + 15) >> 4;
    const int wid = blockIdx.x * 4 + wib;
    const int nw  = gridDim.x * 4;
    for (int tile = wid; tile < nTiles; tile += nw) {
        const int base = tile * 16;
#pragma unroll
        for (int j = 0; j < 16; ++j) {
            int row = min(base + j, nNodes - 1);
            mt[j * 72 + lane] = f2bf(tv[(size_t)row * 64 + lane]);
        }
        __builtin_amdgcn_s_waitcnt(0);   // drains vmcnt too -> safe to zero tv
#pragma unroll
        for (int j = 0; j < 16; ++j) {
            int row = base + j;
            if (row < nNodes) tv[(size_t)row * 64 + lane] = 0.f;
        }
        short8 a0 = *(const short8*)&mt[col * 72 + quad * 8];
        short8 a1 = *(const short8*)&mt[col * 72 + 32 + quad * 8];
#pragma unroll
        for (int nt = 0; nt < 4; ++nt) {
            float4v c = {0.f, 0.f, 0.f, 0.f};
            c = MFMA16(a0, bh[nt][0], c);
            c = MFMA16(a1, bh[nt][1], c);
            c = MFMA16(a0, bl[nt][0], c);
            c = MFMA16(a1, bl[nt][1], c);
#pragma unroll
            for (int r = 0; r < 4; ++r) {
                int row = base + quad * 4 + r;
                if (row < nNodes) {
                    float* hp = &h[(size_t)row * 64 + nt * 16 + col];
                    float hn = *hp + fmaxf(c[r] + bv[nt], 0.f);
                    *hp = hn;
                    cs0 += (nt == 0) ? hn : 0.f;
                    cs1 += (nt == 1) ? hn : 0.f;
                    cs2 += (nt == 2) ? hn : 0.f;
                    cs3 += (nt == 3) ? hn : 0.f;
                }
            }
        }
    }
    if (doCS) {
        cs0 += __shfl_xor(cs0, 16); cs0 += __shfl_xor(cs0, 32);
        cs1 += __shfl_xor(cs1, 16); cs1 += __shfl_xor(cs1, 32);
        cs2 += __shfl_xor(cs2, 16); cs2 += __shfl_xor(cs2, 32);
        cs3 += __shfl_xor(cs3, 16); cs3 += __shfl_xor(cs3, 32);
        const float tot = (quad == 0) ? cs0 : (quad == 1) ? cs1
                        : (quad == 2) ? cs2 : cs3;
        atomicAdd(&colsum[lane], tot);   // lane == quad*16+col
    }
}

// ---------------- edge kernel: 64-edge batches over sorted CSR ----------------
#define EST 72   // ushorts per staged row

__global__ __launch_bounds__(256) void k_edge(const unsigned short* __restrict__ P,
        const unsigned short* __restrict__ Q, const float* __restrict__ ea_s,
        const int* __restrict__ col_src, const int* __restrict__ dst_s,
        const float* __restrict__ w1e,
        const unsigned short* __restrict__ wh, const unsigned short* __restrict__ wl,
        const float* __restrict__ b2,
        float* __restrict__ agg, int nEdges) {
    const int lane = threadIdx.x & 63;
    const int wib  = threadIdx.x >> 6;
    const int wid  = blockIdx.x * 4 + wib;
    const int nw   = gridDim.x * 4;
    const int quad = lane >> 4;
    const int col  = lane & 15;

    __shared__ unsigned short m1b[4][64 * EST];
    unsigned short* __restrict__ mt = m1b[wib];

    float w1ec[6];
#pragma unroll
    for (int j = 0; j < 6; ++j) w1ec[j] = w1e[j * 64 + lane];

    short8 bhi[4][2], blo[4][2];
#pragma unroll
    for (int nt = 0; nt < 4; ++nt)
#pragma unroll
        for (int kf = 0; kf < 2; ++kf) {
            LOADFRAG(bhi[nt][kf], wh, nt, 2, kf);
            LOADFRAG(blo[nt][kf], wl, nt, 2, kf);
        }
    float b2v[4];
#pragma unroll
    for (int nt = 0; nt < 4; ++nt) b2v[nt] = b2[nt * 16 + col];

    // contiguous chunk per wave (dst-sorted CSR)
    const int nBatch = (nEdges + 63) >> 6;
    const int per = nBatch / nw, rem = nBatch % nw;
    const int btLo = wid * per + min(wid, rem);
    const int btHi = btLo + per + (wid < rem ? 1 : 0);

    for (int bt = btLo; bt < btHi; ++bt) {
        const int base = __builtin_amdgcn_readfirstlane(bt << 6);
        const int gidx = min(base + lane, nEdges - 1);
        const int vdj = dst_s[gidx];          // row `lane`'s dst
        const int vsj = col_src[gidx];        // row `lane`'s src
        const int vprev = __shfl_up(vdj, 1);
        unsigned long long bmask = __ballot(lane == 0 || vdj != vprev) | 1ull;

        // ---- stage 64 rows: m1 -> bf16 -> LDS (straight-line, b1 in P) ----
#pragma unroll
        for (int j = 0; j < 64; ++j) {
            const int d = __builtin_amdgcn_readlane(vdj, j);
            const int s = __builtin_amdgcn_readlane(vsj, j);
            const int idx = min(base + j, nEdges - 1);   // uniform
            float t = bf2f(P[(size_t)d * 64 + lane]) +
                      bf2f(Q[(size_t)s * 64 + lane]);
            const float* eap = ea_s + (size_t)idx * 6;
#pragma unroll
            for (int jj = 0; jj < 6; ++jj) t = fmaf(eap[jj], w1ec[jj], t);
            mt[j * EST + lane] = f2bf(fmaxf(t, 0.f));
        }
        __builtin_amdgcn_s_waitcnt(0);   // wave-local LDS drain

        // A-frags for 4 row-tiles
        short8 aT[4][2];
#pragma unroll
        for (int t = 0; t < 4; ++t) {
            aT[t][0] = *(const short8*)&mt[(t * 16 + col) * EST + quad * 8];
            aT[t][1] = *(const short8*)&mt[(t * 16 + col) * EST + 32 + quad * 8];
        }

        // m2 for all 4 tiles, masked+relu'd up front
        float4v m2v[4][4];
#pragma unroll
        for (int nt = 0; nt < 4; ++nt) {
#pragma unroll
            for (int t = 0; t < 4; ++t) {
                float4v c = {0.f, 0.f, 0.f, 0.f};
                c = MFMA16(aT[t][0], bhi[nt][0], c);
                c = MFMA16(aT[t][1], bhi[nt][1], c);
                c = MFMA16(aT[t][0], blo[nt][0], c);
                c = MFMA16(aT[t][1], blo[nt][1], c);
#pragma unroll
                for (int r = 0; r < 4; ++r) {
                    const bool v = base + t * 16 + (quad * 4 + r) < nEdges;
                    m2v[t][nt][r] = v ? fmaxf(c[r] + b2v[nt], 0.f) : 0.f;
                }
            }
        }

        // ---- segmented reduce + one coalesced atomic per segment ----
        int r0 = 0;
        while (r0 < 64) {
            const int nid = __builtin_amdgcn_readlane(vdj, r0);
            unsigned long long rest = (r0 < 63) ? (bmask >> (r0 + 1)) : 0ull;
            const int r1 = rest ? (r0 + 1 + (int)__builtin_ctzll(rest)) : 64;
            float s0 = 0.f, s1 = 0.f, s2 = 0.f, s3 = 0.f;
#pragma unroll
            for (int t = 0; t < 4; ++t)
#pragma unroll
                for (int r = 0; r < 4; ++r) {
                    const int R = t * 16 + quad * 4 + r;
                    const bool in = (R >= r0) && (R < r1);
                    s0 += in ? m2v[t][0][r] : 0.f;
                    s1 += in ? m2v[t][1][r] : 0.f;
                    s2 += in ? m2v[t][2][r] : 0.f;
                    s3 += in ? m2v[t][3][r] : 0.f;
                }
            s0 += __shfl_xor(s0, 16); s0 += __shfl_xor(s0, 32);
            s1 += __shfl_xor(s1, 16); s1 += __shfl_xor(s1, 32);
            s2 += __shfl_xor(s2, 16); s2 += __shfl_xor(s2, 32);
            s3 += __shfl_xor(s3, 16); s3 += __shfl_xor(s3, 32);
            const float tot = (quad == 0) ? s0 : (quad == 1) ? s1
                            : (quad == 2) ? s2 : s3;
            atomicAdd(&agg[(size_t)nid * 64 + lane], tot);
            r0 = r1;
        }
    }
}

__global__ void k_out(const float* __restrict__ colsum, const float* __restrict__ pw,
                      const float* __restrict__ pb, float* __restrict__ out, int nNodes) {
    const int lane = threadIdx.x;
    float v = colsum[lane] * pw[lane];
#pragma unroll
    for (int off = 32; off; off >>= 1) v += __shfl_down(v, off);
    if (lane == 0) out[0] = v + (float)nNodes * pb[0];
}

extern "C" void kernel_launch(void* const* d_in, const int* in_sizes, int n_in,
                              void* d_out, int out_size, void* d_ws, size_t ws_size,
                              hipStream_t stream) {
    const float* x     = (const float*)d_in[0];
    const int*   ei    = (const int*)d_in[1];
    const float* ea    = (const float*)d_in[2];
    const float* lin_w = (const float*)d_in[3];
    const float* lin_b = (const float*)d_in[4];
    const float* mw1   = (const float*)d_in[5];
    const float* mb1   = (const float*)d_in[6];
    const float* mw2   = (const float*)d_in[7];
    const float* mb2   = (const float*)d_in[8];
    const float* uw1   = (const float*)d_in[9];
    const float* ub1   = (const float*)d_in[10];
    const float* uw2   = (const float*)d_in[11];
    const float* ub2   = (const float*)d_in[12];
    const float* pw    = (const float*)d_in[13];
    const float* pb    = (const float*)d_in[14];

    const int nNodes = in_sizes[0] / 128;
    const int nEdges = in_sizes[1] / 2;
    const int* src = ei;            // edge_index[0]
    const int* dst = ei + nEdges;   // edge_index[1]

    // workspace layout (floats, then ushorts, then ints)
    float* h       = (float*)d_ws;
    float* agg     = h   + (size_t)nNodes * 64;   // also tv (in-place upd1)
    float* ea_s    = agg + (size_t)nNodes * 64;
    float* colsum  = ea_s + (size_t)nEdges * 6;
    unsigned short* Pb  = (unsigned short*)(colsum + 64);
    unsigned short* Qb  = Pb + (size_t)nNodes * 64;
    unsigned short* wpH = Qb + (size_t)nNodes * 64;
    unsigned short* wpL = wpH + WP_TOTAL;
    int*   deg     = (int*)(wpL + WP_TOTAL);
    int*   cursor  = deg + nNodes;
    int*   local   = cursor + nNodes;
    int*   bsum    = local + nNodes;
    int*   col_src = bsum + 256;
    int*   dst_s   = col_src + nEdges;

    const int NB_T    = 782;                     // node-GEMM: 1 tile/wave
    const int NB_EDGE = 1024;                    // 4 blocks/CU, LDS-resident
    const int NB_FLAT = (nEdges + 255) / 256;
    const int NB_SCAN = (nNodes + 255) / 256;

    // ---- one-time: CSR build + weight prep ----
    hipMemsetAsync(deg, 0, (size_t)nNodes * sizeof(int), stream);
    hipMemsetAsync(colsum, 0, 64 * sizeof(float), stream);
    hipMemsetAsync(agg, 0, (size_t)nNodes * 64 * sizeof(float), stream);
    k_hist<<<NB_FLAT, 256, 0, stream>>>(dst, deg, nEdges);
    k_scan1<<<NB_SCAN, 256, 0, stream>>>(deg, local, bsum, nNodes);
    k_scan2<<<1, 256, 0, stream>>>(bsum, NB_SCAN);
    k_scan3<<<NB_SCAN, 256, 0, stream>>>(local, bsum, cursor, nNodes);
    k_scatter<<<NB_FLAT, 256, 0, stream>>>(src, dst, ea, cursor, col_src, dst_s, ea_s, nEdges);
    k_wprep<<<(WP_TOTAL + 255) / 256, 256, 0, stream>>>(lin_w, mw1, mw2, uw1, uw2, wpH, wpL);

    k_in<<<NB_T, 256, 0, stream>>>(x, wpH + OFF_IN, wpL + OFF_IN, lin_b, h, nNodes);

    for (int l = 0; l < 4; ++l) {
        k_pre<<<NB_T, 256, 0, stream>>>(h, wpH + OFF_PRE(l), wpL + OFF_PRE(l),
            mb1 + l * 64, Pb, Qb, nNodes);
        k_edge<<<NB_EDGE, 256, 0, stream>>>(Pb, Qb, ea_s, col_src, dst_s,
            mw1 + (size_t)l * 134 * 64 + 128 * 64,
            wpH + OFF_MW2(l), wpL + OFF_MW2(l), mb2 + l * 64, agg, nEdges);
        k_upd1<<<NB_T, 256, 0, stream>>>(h, agg,
            wpH + OFF_UW1(l), wpL + OFF_UW1(l), ub1 + l * 64, agg, nNodes);
        k_upd2<<<NB_T, 256, 0, stream>>>(h, agg,
            wpH + OFF_UW2(l), wpL + OFF_UW2(l), ub2 + l * 64,
            colsum, nNodes, (l == 3) ? 1 : 0);
    }

    k_out<<<1, 64, 0, stream>>>(colsum, pw, pb, (float*)d_out, nNodes);
}

// Round 14
// 757.637 us; speedup vs baseline: 1.1888x; 1.1888x over previous
//
#include <hip/hip_runtime.h>

// MPNN on MI355X.
//
// Algebra: msg layer-1 is linear before its relu:
//   m1 = relu(P[dst] + Q[src] + ea@W1e + b1), P = h@W1[0:64]+b1, Q = h@W1[64:128]
// R3: m2 GEMM via bf16 MFMA (A plain bf16 = random rounding, W hi+lo bf16).
// R4: dst-sorted CSR, consumer-side aggregation (killed 51M fp32 atomics).
// R5-R7: flat 32-edge batches, metadata vector load + v_readlane, ballot
//     segment mask, per-segment coalesced atomic; node GEMMs MFMA-ized.
// R8/R10/R13 (REVERTED): staging-loop restructures and 64-edge batches all
//     lose — this kernel lives on TLP/occupancy (R13: VGPR 116 + LDS 37KB
//     halved resident waves, 86->121us). 32-edge/VGPR-80/18KB is the sweet
//     spot; staging loop stays straight-line.
// R9: P/Q stored bf16. R12: fragment-layout prepped hi/lo weights (-60us).
// R14: R12 exact k_edge; single delta = node grids NB_T 392->782
//     (1 tile/wave, halves node-kernel serial critical path).

typedef __attribute__((ext_vector_type(8))) short short8;
typedef __attribute__((ext_vector_type(4))) float float4v;

__device__ __forceinline__ unsigned short f2bf(float f) {
    unsigned int u = __float_as_uint(f);
    unsigned int r = u + 0x7fff + ((u >> 16) & 1);   // RTNE
    return (unsigned short)(r >> 16);
}
__device__ __forceinline__ float bf2f(unsigned short u) {
    return __uint_as_float(((unsigned int)u) << 16);
}

#define MFMA16(a, b, c) __builtin_amdgcn_mfma_f32_16x16x32_bf16(a, b, c, 0, 0, 0)

struct bfpair { short hi, lo; };
__device__ __forceinline__ bfpair wsplit(float wv) {
    bfpair p;
    unsigned short h = f2bf(wv);
    float hf = __uint_as_float(((unsigned int)h) << 16);
    p.hi = (short)h;
    p.lo = (short)f2bf(wv - hf);
    return p;
}

// fragment-layout weight prep offsets (ushort elements)
#define WP_TOTAL 106496
#define OFF_IN   0
#define OFF_PRE(l)  (8192  + (l) * 8192)
#define OFF_MW2(l)  (40960 + (l) * 4096)
#define OFF_UW1(l)  (57344 + (l) * 8192)
#define OFF_UW2(l)  (90112 + (l) * 4096)

// ---------------- weight prep: fp32 -> hi/lo bf16 in fragment layout ----------------
__global__ __launch_bounds__(256) void k_wprep(const float* __restrict__ lin_w,
        const float* __restrict__ mw1, const float* __restrict__ mw2,
        const float* __restrict__ uw1, const float* __restrict__ uw2,
        unsigned short* __restrict__ H, unsigned short* __restrict__ L) {
    const int tid = blockIdx.x * 256 + threadIdx.x;
    if (tid >= WP_TOTAL) return;
    float val;
    if (tid < 8192) {                                  // lin_in_w: KF=4, NT=4
        int rem = tid;
        int nt = rem >> 11, kf = (rem >> 9) & 3;
        int lane = (rem >> 3) & 63, j = rem & 7;
        int k = kf * 32 + (lane >> 4) * 8 + j;
        val = lin_w[k * 64 + nt * 16 + (lane & 15)];
    } else if (tid < 40960) {                          // msg_w1[0:128]: KF=2, NT=8
        int t = tid - 8192, layer = t >> 13, rem = t & 8191;
        int nt = rem >> 10, kf = (rem >> 9) & 1;
        int lane = (rem >> 3) & 63, j = rem & 7;
        int k = kf * 32 + (lane >> 4) * 8 + j;
        const float* w1 = mw1 + (size_t)layer * 134 * 64;
        val = (nt < 4) ? w1[k * 64 + nt * 16 + (lane & 15)]
                       : w1[(64 + k) * 64 + (nt - 4) * 16 + (lane & 15)];
    } else if (tid < 57344) {                          // msg_w2: KF=2, NT=4
        int t = tid - 40960, layer = t >> 12, rem = t & 4095;
        int nt = rem >> 10, kf = (rem >> 9) & 1;
        int lane = (rem >> 3) & 63, j = rem & 7;
        int k = kf * 32 + (lane >> 4) * 8 + j;
        val = mw2[(size_t)layer * 4096 + k * 64 + nt * 16 + (lane & 15)];
    } else if (tid < 90112) {                          // upd_w1: KF=4, NT=4
        int t = tid - 57344, layer = t >> 13, rem = t & 8191;
        int nt = rem >> 11, kf = (rem >> 9) & 3;
        int lane = (rem >> 3) & 63, j = rem & 7;
        int k = kf * 32 + (lane >> 4) * 8 + j;
        val = uw1[(size_t)layer * 8192 + k * 64 + nt * 16 + (lane & 15)];
    } else {                                           // upd_w2: KF=2, NT=4
        int t = tid - 90112, layer = t >> 12, rem = t & 4095;
        int nt = rem >> 10, kf = (rem >> 9) & 1;
        int lane = (rem >> 3) & 63, j = rem & 7;
        int k = kf * 32 + (lane >> 4) * 8 + j;
        val = uw2[(size_t)layer * 4096 + k * 64 + nt * 16 + (lane & 15)];
    }
    bfpair p = wsplit(val);
    H[tid] = (unsigned short)p.hi;
    L[tid] = (unsigned short)p.lo;
}

#define LOADFRAG(dst, arr, nt, KF, kf) \
    dst = *(const short8*)&arr[((((nt) * (KF)) + (kf)) * 64 + lane) * 8]

// ---------------- CSR build ----------------
__global__ __launch_bounds__(256) void k_hist(const int* __restrict__ dst,
        int* __restrict__ deg, int nEdges) {
    int e = blockIdx.x * blockDim.x + threadIdx.x;
    if (e < nEdges) atomicAdd(&deg[dst[e]], 1);
}

__global__ __launch_bounds__(256) void k_scan1(const int* __restrict__ deg,
        int* __restrict__ local, int* __restrict__ bsum, int nNodes) {
    __shared__ int sm[256];
    const int t = threadIdx.x;
    const int n = blockIdx.x * 256 + t;
    int v = (n < nNodes) ? deg[n] : 0;
    sm[t] = v;
    __syncthreads();
    for (int off = 1; off < 256; off <<= 1) {
        int u = (t >= off) ? sm[t - off] : 0;
        __syncthreads();
        sm[t] += u;
        __syncthreads();
    }
    if (n < nNodes) local[n] = sm[t] - v;
    if (t == 255) bsum[blockIdx.x] = sm[255];
}

__global__ __launch_bounds__(256) void k_scan2(int* __restrict__ bsum, int nB) {
    __shared__ int sm[256];
    const int t = threadIdx.x;
    int v = (t < nB) ? bsum[t] : 0;
    sm[t] = v;
    __syncthreads();
    for (int off = 1; off < 256; off <<= 1) {
        int u = (t >= off) ? sm[t - off] : 0;
        __syncthreads();
        sm[t] += u;
        __syncthreads();
    }
    if (t < nB) bsum[t] = sm[t] - v;
}

__global__ __launch_bounds__(256) void k_scan3(const int* __restrict__ local,
        const int* __restrict__ bsum, int* __restrict__ cursor, int nNodes) {
    int n = blockIdx.x * 256 + threadIdx.x;
    if (n < nNodes) cursor[n] = bsum[blockIdx.x] + local[n];
}

__global__ __launch_bounds__(256) void k_scatter(const int* __restrict__ src,
        const int* __restrict__ dst, const float* __restrict__ ea,
        int* __restrict__ cursor, int* __restrict__ col_src,
        int* __restrict__ dst_s, float* __restrict__ ea_s, int nEdges) {
    int e = blockIdx.x * blockDim.x + threadIdx.x;
    if (e < nEdges) {
        int d = dst[e];
        int pos = atomicAdd(&cursor[d], 1);
        col_src[pos] = src[e];
        dst_s[pos] = d;
        const float* p = ea + (size_t)e * 6;
        float* q = ea_s + (size_t)pos * 6;
#pragma unroll
        for (int j = 0; j < 6; ++j) q[j] = p[j];
    }
}

// ---------------- node-side MFMA GEMM kernels ----------------
// A-frag: A[m=col][k=quad*8+j]; C: col=lane&15, row=quad*4+reg (verified).

// h = x @ Win + b   (K=128, N=64)
__global__ __launch_bounds__(256) void k_in(const float* __restrict__ x,
        const unsigned short* __restrict__ wh, const unsigned short* __restrict__ wl,
        const float* __restrict__ bia, float* __restrict__ h, int nNodes) {
    const int lane = threadIdx.x & 63;
    const int wib  = threadIdx.x >> 6;
    const int quad = lane >> 4, col = lane & 15;
    __shared__ unsigned short sm[4][16 * 136];
    unsigned short* __restrict__ mt = sm[wib];

    short8 bh[4][4], bl[4][4];
#pragma unroll
    for (int nt = 0; nt < 4; ++nt)
#pragma unroll
        for (int kf = 0; kf < 4; ++kf) {
            LOADFRAG(bh[nt][kf], wh, nt, 4, kf);
            LOADFRAG(bl[nt][kf], wl, nt, 4, kf);
        }
    float bv[4];
#pragma unroll
    for (int nt = 0; nt < 4; ++nt) bv[nt] = bia[nt * 16 + col];

    const int nTiles = (nNodes + 15) >> 4;
    const int wid = blockIdx.x * 4 + wib;
    const int nw  = gridDim.x * 4;
    for (int tile = wid; tile < nTiles; tile += nw) {
        const int base = tile * 16;
#pragma unroll
        for (int j = 0; j < 16; ++j) {
            int row = min(base + j, nNodes - 1);
            mt[j * 136 + lane]      = f2bf(x[(size_t)row * 128 + lane]);
            mt[j * 136 + 64 + lane] = f2bf(x[(size_t)row * 128 + 64 + lane]);
        }
        __builtin_amdgcn_s_waitcnt(0);
        short8 a[4];
#pragma unroll
        for (int kf = 0; kf < 4; ++kf)
            a[kf] = *(const short8*)&mt[col * 136 + kf * 32 + quad * 8];
#pragma unroll
        for (int nt = 0; nt < 4; ++nt) {
            float4v c = {0.f, 0.f, 0.f, 0.f};
#pragma unroll
            for (int kf = 0; kf < 4; ++kf) c = MFMA16(a[kf], bh[nt][kf], c);
#pragma unroll
            for (int kf = 0; kf < 4; ++kf) c = MFMA16(a[kf], bl[nt][kf], c);
#pragma unroll
            for (int r = 0; r < 4; ++r) {
                int row = base + quad * 4 + r;
                if (row < nNodes)
                    h[(size_t)row * 64 + nt * 16 + col] = c[r] + bv[nt];
            }
        }
    }
}

// [P|Q] = h @ [W1[0:64] | W1[64:128]]; P += b1   (K=64, N=128), bf16 outputs
__global__ __launch_bounds__(256) void k_pre(const float* __restrict__ h,
        const unsigned short* __restrict__ wh, const unsigned short* __restrict__ wl,
        const float* __restrict__ b1m,
        unsigned short* __restrict__ P, unsigned short* __restrict__ Q,
        int nNodes) {
    const int lane = threadIdx.x & 63;
    const int wib  = threadIdx.x >> 6;
    const int quad = lane >> 4, col = lane & 15;
    __shared__ unsigned short sm[4][16 * 72];
    unsigned short* __restrict__ mt = sm[wib];

    short8 bh[8][2], bl[8][2];
#pragma unroll
    for (int nt = 0; nt < 8; ++nt)
#pragma unroll
        for (int kf = 0; kf < 2; ++kf) {
            LOADFRAG(bh[nt][kf], wh, nt, 2, kf);
            LOADFRAG(bl[nt][kf], wl, nt, 2, kf);
        }
    float bv1[4];
#pragma unroll
    for (int nt = 0; nt < 4; ++nt) bv1[nt] = b1m[nt * 16 + col];

    const int nTiles = (nNodes + 15) >> 4;
    const int wid = blockIdx.x * 4 + wib;
    const int nw  = gridDim.x * 4;
    for (int tile = wid; tile < nTiles; tile += nw) {
        const int base = tile * 16;
#pragma unroll
        for (int j = 0; j < 16; ++j) {
            int row = min(base + j, nNodes - 1);
            mt[j * 72 + lane] = f2bf(h[(size_t)row * 64 + lane]);
        }
        __builtin_amdgcn_s_waitcnt(0);
        short8 a0 = *(const short8*)&mt[col * 72 + quad * 8];
        short8 a1 = *(const short8*)&mt[col * 72 + 32 + quad * 8];
#pragma unroll
        for (int nt = 0; nt < 8; ++nt) {
            float4v c = {0.f, 0.f, 0.f, 0.f};
            c = MFMA16(a0, bh[nt][0], c);
            c = MFMA16(a1, bh[nt][1], c);
            c = MFMA16(a0, bl[nt][0], c);
            c = MFMA16(a1, bl[nt][1], c);
            unsigned short* __restrict__ outp = (nt < 4) ? P : Q;
            const int nc = (nt & 3) * 16 + col;
            const float badd = (nt < 4) ? bv1[nt & 3] : 0.f;
#pragma unroll
            for (int r = 0; r < 4; ++r) {
                int row = base + quad * 4 + r;
                if (row < nNodes) outp[(size_t)row * 64 + nc] = f2bf(c[r] + badd);
            }
        }
    }
}

// tv = relu([h|agg] @ U1 + b1)   (K=128, N=64); tv aliases agg (in-place)
__global__ __launch_bounds__(256) void k_upd1(const float* __restrict__ h,
        const float* __restrict__ agg,
        const unsigned short* __restrict__ wh, const unsigned short* __restrict__ wl,
        const float* __restrict__ b1, float* __restrict__ tv, int nNodes) {
    const int lane = threadIdx.x & 63;
    const int wib  = threadIdx.x >> 6;
    const int quad = lane >> 4, col = lane & 15;
    __shared__ unsigned short sm[4][16 * 136];
    unsigned short* __restrict__ mt = sm[wib];

    short8 bh[4][4], bl[4][4];
#pragma unroll
    for (int nt = 0; nt < 4; ++nt)
#pragma unroll
        for (int kf = 0; kf < 4; ++kf) {
            LOADFRAG(bh[nt][kf], wh, nt, 4, kf);
            LOADFRAG(bl[nt][kf], wl, nt, 4, kf);
        }
    float bv[4];
#pragma unroll
    for (int nt = 0; nt < 4; ++nt) bv[nt] = b1[nt * 16 + col];

    const int nTiles = (nNodes + 15) >> 4;
    const int wid = blockIdx.x * 4 + wib;
    const int nw  = gridDim.x * 4;
    for (int tile = wid; tile < nTiles; tile += nw) {
        const int base = tile * 16;
#pragma unroll
        for (int j = 0; j < 16; ++j) {
            int row = min(base + j, nNodes - 1);
            mt[j * 136 + lane]      = f2bf(h[(size_t)row * 64 + lane]);
            mt[j * 136 + 64 + lane] = f2bf(agg[(size_t)row * 64 + lane]);
        }
        __builtin_amdgcn_s_waitcnt(0);
        short8 a[4];
#pragma unroll
        for (int kf = 0; kf < 4; ++kf)
            a[kf] = *(const short8*)&mt[col * 136 + kf * 32 + quad * 8];
#pragma unroll
        for (int nt = 0; nt < 4; ++nt) {
            float4v c = {0.f, 0.f, 0.f, 0.f};
#pragma unroll
            for (int kf = 0; kf < 4; ++kf) c = MFMA16(a[kf], bh[nt][kf], c);
#pragma unroll
            for (int kf = 0; kf < 4; ++kf) c = MFMA16(a[kf], bl[nt][kf], c);
#pragma unroll
            for (int r = 0; r < 4; ++r) {
                int row = base + quad * 4 + r;
                if (row < nNodes)
                    tv[(size_t)row * 64 + nt * 16 + col] = fmaxf(c[r] + bv[nt], 0.f);
            }
        }
    }
}

// h += relu(tv @ U2 + b2); zero tv(=agg) for next layer; optional colsum
__global__ __launch_bounds__(256) void k_upd2(float* __restrict__ h,
        float* __restrict__ tv,
        const unsigned short* __restrict__ wh, const unsigned short* __restrict__ wl,
        const float* __restrict__ b2, float* __restrict__ colsum,
        int nNodes, int doCS) {
    const int lane = threadIdx.x & 63;
    const int wib  = threadIdx.x >> 6;
    const int quad = lane >> 4, col = lane & 15;
    __shared__ unsigned short sm[4][16 * 72];
    unsigned short* __restrict__ mt = sm[wib];

    short8 bh[4][2], bl[4][2];
#pragma unroll
    for (int nt = 0; nt < 4; ++nt)
#pragma unroll
        for (int kf = 0; kf < 2; ++kf) {
            LOADFRAG(bh[nt][kf], wh, nt, 2, kf);
            LOADFRAG(bl[nt][kf], wl, nt, 2, kf);
        }
    float bv[4];
#pragma unroll
    for (int nt = 0; nt < 4; ++nt) bv[nt] = b2[nt * 16 + col];

    float cs0 = 0.f, cs1 = 0.f, cs2 = 0.f, cs3 = 0.f;
    const int nTiles = (nNodes + 15) >> 4;
    const int wid = blockIdx.x * 4 + wib;
    const int nw  = gridDim.x * 4;
    for (int tile = wid; tile < nTiles; tile += nw) {
        const int base = tile * 16;
#pragma unroll
        for (int j = 0; j < 16; ++j) {
            int row = min(base + j, nNodes - 1);
            mt[j * 72 + lane] = f2bf(tv[(size_t)row * 64 + lane]);
        }
        __builtin_amdgcn_s_waitcnt(0);   // drains vmcnt too -> safe to zero tv
#pragma unroll
        for (int j = 0; j < 16; ++j) {
            int row = base + j;
            if (row < nNodes) tv[(size_t)row * 64 + lane] = 0.f;
        }
        short8 a0 = *(const short8*)&mt[col * 72 + quad * 8];
        short8 a1 = *(const short8*)&mt[col * 72 + 32 + quad * 8];
#pragma unroll
        for (int nt = 0; nt < 4; ++nt) {
            float4v c = {0.f, 0.f, 0.f, 0.f};
            c = MFMA16(a0, bh[nt][0], c);
            c = MFMA16(a1, bh[nt][1], c);
            c = MFMA16(a0, bl[nt][0], c);
            c = MFMA16(a1, bl[nt][1], c);
#pragma unroll
            for (int r = 0; r < 4; ++r) {
                int row = base + quad * 4 + r;
                if (row < nNodes) {
                    float* hp = &h[(size_t)row * 64 + nt * 16 + col];
                    float hn = *hp + fmaxf(c[r] + bv[nt], 0.f);
                    *hp = hn;
                    cs0 += (nt == 0) ? hn : 0.f;
                    cs1 += (nt == 1) ? hn : 0.f;
                    cs2 += (nt == 2) ? hn : 0.f;
                    cs3 += (nt == 3) ? hn : 0.f;
                }
            }
        }
    }
    if (doCS) {
        cs0 += __shfl_xor(cs0, 16); cs0 += __shfl_xor(cs0, 32);
        cs1 += __shfl_xor(cs1, 16); cs1 += __shfl_xor(cs1, 32);
        cs2 += __shfl_xor(cs2, 16); cs2 += __shfl_xor(cs2, 32);
        cs3 += __shfl_xor(cs3, 16); cs3 += __shfl_xor(cs3, 32);
        const float tot = (quad == 0) ? cs0 : (quad == 1) ? cs1
                        : (quad == 2) ? cs2 : cs3;
        atomicAdd(&colsum[lane], tot);   // lane == quad*16+col
    }
}

// ---------------- edge kernel: contiguous-chunk 32-edge batches ----------------
#define EST 72   // ushorts per staged row

__global__ __launch_bounds__(256) void k_edge(const unsigned short* __restrict__ P,
        const unsigned short* __restrict__ Q, const float* __restrict__ ea_s,
        const int* __restrict__ col_src, const int* __restrict__ dst_s,
        const float* __restrict__ w1e,
        const unsigned short* __restrict__ wh, const unsigned short* __restrict__ wl,
        const float* __restrict__ b2,
        float* __restrict__ agg, int nEdges) {
    const int lane = threadIdx.x & 63;
    const int wib  = threadIdx.x >> 6;
    const int wid  = blockIdx.x * 4 + wib;
    const int nw   = gridDim.x * 4;
    const int quad = lane >> 4;
    const int col  = lane & 15;
    const int li   = lane & 31;

    __shared__ unsigned short m1b[4][32 * EST];
    unsigned short* __restrict__ mt = m1b[wib];

    float w1ec[6];
#pragma unroll
    for (int j = 0; j < 6; ++j) w1ec[j] = w1e[j * 64 + lane];

    short8 bhi[4][2], blo[4][2];
#pragma unroll
    for (int nt = 0; nt < 4; ++nt)
#pragma unroll
        for (int kf = 0; kf < 2; ++kf) {
            LOADFRAG(bhi[nt][kf], wh, nt, 2, kf);
            LOADFRAG(blo[nt][kf], wl, nt, 2, kf);
        }
    float b2v[4];
#pragma unroll
    for (int nt = 0; nt < 4; ++nt) b2v[nt] = b2[nt * 16 + col];

    // contiguous chunk per wave: dst-sorted CSR -> P/agg locality
    const int nBatch = (nEdges + 31) >> 5;
    const int per = nBatch / nw, rem = nBatch % nw;
    const int btLo = wid * per + min(wid, rem);
    const int btHi = btLo + per + (wid < rem ? 1 : 0);

    for (int bt = btLo; bt < btHi; ++bt) {
        const int base = __builtin_amdgcn_readfirstlane(bt << 5);
        const int gidx = min(base + li, nEdges - 1);
        const int vdj = dst_s[gidx];          // row li's dst (lanes 32-63 dup)
        const int vsj = col_src[gidx];        // row li's src
        const int vprev = __shfl_up(vdj, 1);
        unsigned long long bmask =
            __ballot(lane < 32 && (li == 0 || vdj != vprev));
        bmask |= (1ull << 32) | 1ull;

        // ---- stage 32 rows: m1 -> bf16 -> LDS (straight-line, b1 in P) ----
#pragma unroll
        for (int j = 0; j < 32; ++j) {
            const int d = __builtin_amdgcn_readlane(vdj, j);
            const int s = __builtin_amdgcn_readlane(vsj, j);
            const int idx = min(base + j, nEdges - 1);   // uniform
            float t = bf2f(P[(size_t)d * 64 + lane]) +
                      bf2f(Q[(size_t)s * 64 + lane]);
            const float* eap = ea_s + (size_t)idx * 6;
#pragma unroll
            for (int jj = 0; jj < 6; ++jj) t = fmaf(eap[jj], w1ec[jj], t);
            mt[j * EST + lane] = f2bf(fmaxf(t, 0.f));
        }
        __builtin_amdgcn_s_waitcnt(0);   // wave-local LDS drain

        short8 a00 = *(const short8*)&mt[col * EST + quad * 8];
        short8 a01 = *(const short8*)&mt[col * EST + 32 + quad * 8];
        short8 a10 = *(const short8*)&mt[(16 + col) * EST + quad * 8];
        short8 a11 = *(const short8*)&mt[(16 + col) * EST + 32 + quad * 8];

        // m2 for both 16-row tiles, masked+relu'd up front
        float4v m2v[2][4];
#pragma unroll
        for (int nt = 0; nt < 4; ++nt) {
            float4v c0 = {0.f, 0.f, 0.f, 0.f};
            float4v c1 = {0.f, 0.f, 0.f, 0.f};
            c0 = MFMA16(a00, bhi[nt][0], c0);
            c0 = MFMA16(a01, bhi[nt][1], c0);
            c0 = MFMA16(a00, blo[nt][0], c0);
            c0 = MFMA16(a01, blo[nt][1], c0);
            c1 = MFMA16(a10, bhi[nt][0], c1);
            c1 = MFMA16(a11, bhi[nt][1], c1);
            c1 = MFMA16(a10, blo[nt][0], c1);
            c1 = MFMA16(a11, blo[nt][1], c1);
#pragma unroll
            for (int r = 0; r < 4; ++r) {
                const bool v0 = base + (quad * 4 + r) < nEdges;
                const bool v1 = base + 16 + (quad * 4 + r) < nEdges;
                m2v[0][nt][r] = v0 ? fmaxf(c0[r] + b2v[nt], 0.f) : 0.f;
                m2v[1][nt][r] = v1 ? fmaxf(c1[r] + b2v[nt], 0.f) : 0.f;
            }
        }

        // ---- segmented reduce + one coalesced atomic per segment ----
        int r0 = 0;
        while (r0 < 32) {
            const int nid = __builtin_amdgcn_readlane(vdj, r0);
            const int r1 = r0 + 1 + (int)__builtin_ctzll(bmask >> (r0 + 1));
            float s0 = 0.f, s1 = 0.f, s2 = 0.f, s3 = 0.f;
#pragma unroll
            for (int t = 0; t < 2; ++t)
#pragma unroll
                for (int r = 0; r < 4; ++r) {
                    const int R = t * 16 + quad * 4 + r;
                    const bool in = (R >= r0) && (R < r1);
                    s0 += in ? m2v[t][0][r] : 0.f;
                    s1 += in ? m2v[t][1][r] : 0.f;
                    s2 += in ? m2v[t][2][r] : 0.f;
                    s3 += in ? m2v[t][3][r] : 0.f;
                }
            s0 += __shfl_xor(s0, 16); s0 += __shfl_xor(s0, 32);
            s1 += __shfl_xor(s1, 16); s1 += __shfl_xor(s1, 32);
            s2 += __shfl_xor(s2, 16); s2 += __shfl_xor(s2, 32);
            s3 += __shfl_xor(s3, 16); s3 += __shfl_xor(s3, 32);
            const float tot = (quad == 0) ? s0 : (quad == 1) ? s1
                            : (quad == 2) ? s2 : s3;
            atomicAdd(&agg[(size_t)nid * 64 + lane], tot);
            r0 = r1;
        }
    }
}

__global__ void k_out(const float* __restrict__ colsum, const float* __restrict__ pw,
                      const float* __restrict__ pb, float* __restrict__ out, int nNodes) {
    const int lane = threadIdx.x;
    float v = colsum[lane] * pw[lane];
#pragma unroll
    for (int off = 32; off; off >>= 1) v += __shfl_down(v, off);
    if (lane == 0) out[0] = v + (float)nNodes * pb[0];
}

extern "C" void kernel_launch(void* const* d_in, const int* in_sizes, int n_in,
                              void* d_out, int out_size, void* d_ws, size_t ws_size,
                              hipStream_t stream) {
    const float* x     = (const float*)d_in[0];
    const int*   ei    = (const int*)d_in[1];
    const float* ea    = (const float*)d_in[2];
    const float* lin_w = (const float*)d_in[3];
    const float* lin_b = (const float*)d_in[4];
    const float* mw1   = (const float*)d_in[5];
    const float* mb1   = (const float*)d_in[6];
    const float* mw2   = (const float*)d_in[7];
    const float* mb2   = (const float*)d_in[8];
    const float* uw1   = (const float*)d_in[9];
    const float* ub1   = (const float*)d_in[10];
    const float* uw2   = (const float*)d_in[11];
    const float* ub2   = (const float*)d_in[12];
    const float* pw    = (const float*)d_in[13];
    const float* pb    = (const float*)d_in[14];

    const int nNodes = in_sizes[0] / 128;
    const int nEdges = in_sizes[1] / 2;
    const int* src = ei;            // edge_index[0]
    const int* dst = ei + nEdges;   // edge_index[1]

    // workspace layout (floats, then ushorts, then ints)
    float* h       = (float*)d_ws;
    float* agg     = h   + (size_t)nNodes * 64;   // also tv (in-place upd1)
    float* ea_s    = agg + (size_t)nNodes * 64;
    float* colsum  = ea_s + (size_t)nEdges * 6;
    unsigned short* Pb  = (unsigned short*)(colsum + 64);
    unsigned short* Qb  = Pb + (size_t)nNodes * 64;
    unsigned short* wpH = Qb + (size_t)nNodes * 64;
    unsigned short* wpL = wpH + WP_TOTAL;
    int*   deg     = (int*)(wpL + WP_TOTAL);
    int*   cursor  = deg + nNodes;
    int*   local   = cursor + nNodes;
    int*   bsum    = local + nNodes;
    int*   col_src = bsum + 256;
    int*   dst_s   = col_src + nEdges;

    const int NB_T    = 782;                     // node-GEMM: 1 tile/wave
    const int NB_EDGE = 2048;
    const int NB_FLAT = (nEdges + 255) / 256;
    const int NB_SCAN = (nNodes + 255) / 256;

    // ---- one-time: CSR build + weight prep ----
    hipMemsetAsync(deg, 0, (size_t)nNodes * sizeof(int), stream);
    hipMemsetAsync(colsum, 0, 64 * sizeof(float), stream);
    hipMemsetAsync(agg, 0, (size_t)nNodes * 64 * sizeof(float), stream);
    k_hist<<<NB_FLAT, 256, 0, stream>>>(dst, deg, nEdges);
    k_scan1<<<NB_SCAN, 256, 0, stream>>>(deg, local, bsum, nNodes);
    k_scan2<<<1, 256, 0, stream>>>(bsum, NB_SCAN);
    k_scan3<<<NB_SCAN, 256, 0, stream>>>(local, bsum, cursor, nNodes);
    k_scatter<<<NB_FLAT, 256, 0, stream>>>(src, dst, ea, cursor, col_src, dst_s, ea_s, nEdges);
    k_wprep<<<(WP_TOTAL + 255) / 256, 256, 0, stream>>>(lin_w, mw1, mw2, uw1, uw2, wpH, wpL);

    k_in<<<NB_T, 256, 0, stream>>>(x, wpH + OFF_IN, wpL + OFF_IN, lin_b, h, nNodes);

    for (int l = 0; l < 4; ++l) {
        k_pre<<<NB_T, 256, 0, stream>>>(h, wpH + OFF_PRE(l), wpL + OFF_PRE(l),
            mb1 + l * 64, Pb, Qb, nNodes);
        k_edge<<<NB_EDGE, 256, 0, stream>>>(Pb, Qb, ea_s, col_src, dst_s,
            mw1 + (size_t)l * 134 * 64 + 128 * 64,
            wpH + OFF_MW2(l), wpL + OFF_MW2(l), mb2 + l * 64, agg, nEdges);
        k_upd1<<<NB_T, 256, 0, stream>>>(h, agg,
            wpH + OFF_UW1(l), wpL + OFF_UW1(l), ub1 + l * 64, agg, nNodes);
        k_upd2<<<NB_T, 256, 0, stream>>>(h, agg,
            wpH + OFF_UW2(l), wpL + OFF_UW2(l), ub2 + l * 64,
            colsum, nNodes, (l == 3) ? 1 : 0);
    }

    k_out<<<1, 64, 0, stream>>>(colsum, pw, pb, (float*)d_out, nNodes);
}

// Round 15
// 708.686 us; speedup vs baseline: 1.2709x; 1.0691x over previous
//
#include <hip/hip_runtime.h>

// MPNN on MI355X.
//
// Algebra: msg layer-1 is linear before its relu:
//   m1 = relu(P[dst] + Q[src] + ea@W1e + b1), P = h@W1[0:64]+b1, Q = h@W1[64:128]
// R3: m2 GEMM via bf16 MFMA (A plain bf16 = random rounding, W hi+lo bf16).
// R4: dst-sorted CSR, consumer-side aggregation (killed 51M fp32 atomics).
// R5-R7: flat 32-edge batches, metadata vector load + v_readlane, ballot
//     segment mask, per-segment coalesced atomic; node GEMMs MFMA-ized.
// R8/R10/R13/R14 (REVERTED): staging-loop restructures, 64-edge batches,
//     and 1-tile/wave node grids all lose — kernels here live on
//     TLP/occupancy + prologue amortization. 32-edge/VGPR-80/18KB k_edge and
//     2-tiles/wave node grids (NB_T=392) are the measured sweet spots.
// R9: P/Q stored bf16. R12: fragment-layout prepped hi/lo weights (-60us).
// R15: exact R12 restore (the 709us best): NB_T back to 392.

typedef __attribute__((ext_vector_type(8))) short short8;
typedef __attribute__((ext_vector_type(4))) float float4v;

__device__ __forceinline__ unsigned short f2bf(float f) {
    unsigned int u = __float_as_uint(f);
    unsigned int r = u + 0x7fff + ((u >> 16) & 1);   // RTNE
    return (unsigned short)(r >> 16);
}
__device__ __forceinline__ float bf2f(unsigned short u) {
    return __uint_as_float(((unsigned int)u) << 16);
}

#define MFMA16(a, b, c) __builtin_amdgcn_mfma_f32_16x16x32_bf16(a, b, c, 0, 0, 0)

struct bfpair { short hi, lo; };
__device__ __forceinline__ bfpair wsplit(float wv) {
    bfpair p;
    unsigned short h = f2bf(wv);
    float hf = __uint_as_float(((unsigned int)h) << 16);
    p.hi = (short)h;
    p.lo = (short)f2bf(wv - hf);
    return p;
}

// fragment-layout weight prep offsets (ushort elements)
#define WP_TOTAL 106496
#define OFF_IN   0
#define OFF_PRE(l)  (8192  + (l) * 8192)
#define OFF_MW2(l)  (40960 + (l) * 4096)
#define OFF_UW1(l)  (57344 + (l) * 8192)
#define OFF_UW2(l)  (90112 + (l) * 4096)

// ---------------- weight prep: fp32 -> hi/lo bf16 in fragment layout ----------------
__global__ __launch_bounds__(256) void k_wprep(const float* __restrict__ lin_w,
        const float* __restrict__ mw1, const float* __restrict__ mw2,
        const float* __restrict__ uw1, const float* __restrict__ uw2,
        unsigned short* __restrict__ H, unsigned short* __restrict__ L) {
    const int tid = blockIdx.x * 256 + threadIdx.x;
    if (tid >= WP_TOTAL) return;
    float val;
    if (tid < 8192) {                                  // lin_in_w: KF=4, NT=4
        int rem = tid;
        int nt = rem >> 11, kf = (rem >> 9) & 3;
        int lane = (rem >> 3) & 63, j = rem & 7;
        int k = kf * 32 + (lane >> 4) * 8 + j;
        val = lin_w[k * 64 + nt * 16 + (lane & 15)];
    } else if (tid < 40960) {                          // msg_w1[0:128]: KF=2, NT=8
        int t = tid - 8192, layer = t >> 13, rem = t & 8191;
        int nt = rem >> 10, kf = (rem >> 9) & 1;
        int lane = (rem >> 3) & 63, j = rem & 7;
        int k = kf * 32 + (lane >> 4) * 8 + j;
        const float* w1 = mw1 + (size_t)layer * 134 * 64;
        val = (nt < 4) ? w1[k * 64 + nt * 16 + (lane & 15)]
                       : w1[(64 + k) * 64 + (nt - 4) * 16 + (lane & 15)];
    } else if (tid < 57344) {                          // msg_w2: KF=2, NT=4
        int t = tid - 40960, layer = t >> 12, rem = t & 4095;
        int nt = rem >> 10, kf = (rem >> 9) & 1;
        int lane = (rem >> 3) & 63, j = rem & 7;
        int k = kf * 32 + (lane >> 4) * 8 + j;
        val = mw2[(size_t)layer * 4096 + k * 64 + nt * 16 + (lane & 15)];
    } else if (tid < 90112) {                          // upd_w1: KF=4, NT=4
        int t = tid - 57344, layer = t >> 13, rem = t & 8191;
        int nt = rem >> 11, kf = (rem >> 9) & 3;
        int lane = (rem >> 3) & 63, j = rem & 7;
        int k = kf * 32 + (lane >> 4) * 8 + j;
        val = uw1[(size_t)layer * 8192 + k * 64 + nt * 16 + (lane & 15)];
    } else {                                           // upd_w2: KF=2, NT=4
        int t = tid - 90112, layer = t >> 12, rem = t & 4095;
        int nt = rem >> 10, kf = (rem >> 9) & 1;
        int lane = (rem >> 3) & 63, j = rem & 7;
        int k = kf * 32 + (lane >> 4) * 8 + j;
        val = uw2[(size_t)layer * 4096 + k * 64 + nt * 16 + (lane & 15)];
    }
    bfpair p = wsplit(val);
    H[tid] = (unsigned short)p.hi;
    L[tid] = (unsigned short)p.lo;
}

#define LOADFRAG(dst, arr, nt, KF, kf) \
    dst = *(const short8*)&arr[((((nt) * (KF)) + (kf)) * 64 + lane) * 8]

// ---------------- CSR build ----------------
__global__ __launch_bounds__(256) void k_hist(const int* __restrict__ dst,
        int* __restrict__ deg, int nEdges) {
    int e = blockIdx.x * blockDim.x + threadIdx.x;
    if (e < nEdges) atomicAdd(&deg[dst[e]], 1);
}

__global__ __launch_bounds__(256) void k_scan1(const int* __restrict__ deg,
        int* __restrict__ local, int* __restrict__ bsum, int nNodes) {
    __shared__ int sm[256];
    const int t = threadIdx.x;
    const int n = blockIdx.x * 256 + t;
    int v = (n < nNodes) ? deg[n] : 0;
    sm[t] = v;
    __syncthreads();
    for (int off = 1; off < 256; off <<= 1) {
        int u = (t >= off) ? sm[t - off] : 0;
        __syncthreads();
        sm[t] += u;
        __syncthreads();
    }
    if (n < nNodes) local[n] = sm[t] - v;
    if (t == 255) bsum[blockIdx.x] = sm[255];
}

__global__ __launch_bounds__(256) void k_scan2(int* __restrict__ bsum, int nB) {
    __shared__ int sm[256];
    const int t = threadIdx.x;
    int v = (t < nB) ? bsum[t] : 0;
    sm[t] = v;
    __syncthreads();
    for (int off = 1; off < 256; off <<= 1) {
        int u = (t >= off) ? sm[t - off] : 0;
        __syncthreads();
        sm[t] += u;
        __syncthreads();
    }
    if (t < nB) bsum[t] = sm[t] - v;
}

__global__ __launch_bounds__(256) void k_scan3(const int* __restrict__ local,
        const int* __restrict__ bsum, int* __restrict__ cursor, int nNodes) {
    int n = blockIdx.x * 256 + threadIdx.x;
    if (n < nNodes) cursor[n] = bsum[blockIdx.x] + local[n];
}

__global__ __launch_bounds__(256) void k_scatter(const int* __restrict__ src,
        const int* __restrict__ dst, const float* __restrict__ ea,
        int* __restrict__ cursor, int* __restrict__ col_src,
        int* __restrict__ dst_s, float* __restrict__ ea_s, int nEdges) {
    int e = blockIdx.x * blockDim.x + threadIdx.x;
    if (e < nEdges) {
        int d = dst[e];
        int pos = atomicAdd(&cursor[d], 1);
        col_src[pos] = src[e];
        dst_s[pos] = d;
        const float* p = ea + (size_t)e * 6;
        float* q = ea_s + (size_t)pos * 6;
#pragma unroll
        for (int j = 0; j < 6; ++j) q[j] = p[j];
    }
}

// ---------------- node-side MFMA GEMM kernels ----------------
// A-frag: A[m=col][k=quad*8+j]; C: col=lane&15, row=quad*4+reg (verified).

// h = x @ Win + b   (K=128, N=64)
__global__ __launch_bounds__(256) void k_in(const float* __restrict__ x,
        const unsigned short* __restrict__ wh, const unsigned short* __restrict__ wl,
        const float* __restrict__ bia, float* __restrict__ h, int nNodes) {
    const int lane = threadIdx.x & 63;
    const int wib  = threadIdx.x >> 6;
    const int quad = lane >> 4, col = lane & 15;
    __shared__ unsigned short sm[4][16 * 136];
    unsigned short* __restrict__ mt = sm[wib];

    short8 bh[4][4], bl[4][4];
#pragma unroll
    for (int nt = 0; nt < 4; ++nt)
#pragma unroll
        for (int kf = 0; kf < 4; ++kf) {
            LOADFRAG(bh[nt][kf], wh, nt, 4, kf);
            LOADFRAG(bl[nt][kf], wl, nt, 4, kf);
        }
    float bv[4];
#pragma unroll
    for (int nt = 0; nt < 4; ++nt) bv[nt] = bia[nt * 16 + col];

    const int nTiles = (nNodes + 15) >> 4;
    const int wid = blockIdx.x * 4 + wib;
    const int nw  = gridDim.x * 4;
    for (int tile = wid; tile < nTiles; tile += nw) {
        const int base = tile * 16;
#pragma unroll
        for (int j = 0; j < 16; ++j) {
            int row = min(base + j, nNodes - 1);
            mt[j * 136 + lane]      = f2bf(x[(size_t)row * 128 + lane]);
            mt[j * 136 + 64 + lane] = f2bf(x[(size_t)row * 128 + 64 + lane]);
        }
        __builtin_amdgcn_s_waitcnt(0);
        short8 a[4];
#pragma unroll
        for (int kf = 0; kf < 4; ++kf)
            a[kf] = *(const short8*)&mt[col * 136 + kf * 32 + quad * 8];
#pragma unroll
        for (int nt = 0; nt < 4; ++nt) {
            float4v c = {0.f, 0.f, 0.f, 0.f};
#pragma unroll
            for (int kf = 0; kf < 4; ++kf) c = MFMA16(a[kf], bh[nt][kf], c);
#pragma unroll
            for (int kf = 0; kf < 4; ++kf) c = MFMA16(a[kf], bl[nt][kf], c);
#pragma unroll
            for (int r = 0; r < 4; ++r) {
                int row = base + quad * 4 + r;
                if (row < nNodes)
                    h[(size_t)row * 64 + nt * 16 + col] = c[r] + bv[nt];
            }
        }
    }
}

// [P|Q] = h @ [W1[0:64] | W1[64:128]]; P += b1   (K=64, N=128), bf16 outputs
__global__ __launch_bounds__(256) void k_pre(const float* __restrict__ h,
        const unsigned short* __restrict__ wh, const unsigned short* __restrict__ wl,
        const float* __restrict__ b1m,
        unsigned short* __restrict__ P, unsigned short* __restrict__ Q,
        int nNodes) {
    const int lane = threadIdx.x & 63;
    const int wib  = threadIdx.x >> 6;
    const int quad = lane >> 4, col = lane & 15;
    __shared__ unsigned short sm[4][16 * 72];
    unsigned short* __restrict__ mt = sm[wib];

    short8 bh[8][2], bl[8][2];
#pragma unroll
    for (int nt = 0; nt < 8; ++nt)
#pragma unroll
        for (int kf = 0; kf < 2; ++kf) {
            LOADFRAG(bh[nt][kf], wh, nt, 2, kf);
            LOADFRAG(bl[nt][kf], wl, nt, 2, kf);
        }
    float bv1[4];
#pragma unroll
    for (int nt = 0; nt < 4; ++nt) bv1[nt] = b1m[nt * 16 + col];

    const int nTiles = (nNodes + 15) >> 4;
    const int wid = blockIdx.x * 4 + wib;
    const int nw  = gridDim.x * 4;
    for (int tile = wid; tile < nTiles; tile += nw) {
        const int base = tile * 16;
#pragma unroll
        for (int j = 0; j < 16; ++j) {
            int row = min(base + j, nNodes - 1);
            mt[j * 72 + lane] = f2bf(h[(size_t)row * 64 + lane]);
        }
        __builtin_amdgcn_s_waitcnt(0);
        short8 a0 = *(const short8*)&mt[col * 72 + quad * 8];
        short8 a1 = *(const short8*)&mt[col * 72 + 32 + quad * 8];
#pragma unroll
        for (int nt = 0; nt < 8; ++nt) {
            float4v c = {0.f, 0.f, 0.f, 0.f};
            c = MFMA16(a0, bh[nt][0], c);
            c = MFMA16(a1, bh[nt][1], c);
            c = MFMA16(a0, bl[nt][0], c);
            c = MFMA16(a1, bl[nt][1], c);
            unsigned short* __restrict__ outp = (nt < 4) ? P : Q;
            const int nc = (nt & 3) * 16 + col;
            const float badd = (nt < 4) ? bv1[nt & 3] : 0.f;
#pragma unroll
            for (int r = 0; r < 4; ++r) {
                int row = base + quad * 4 + r;
                if (row < nNodes) outp[(size_t)row * 64 + nc] = f2bf(c[r] + badd);
            }
        }
    }
}

// tv = relu([h|agg] @ U1 + b1)   (K=128, N=64); tv aliases agg (in-place)
__global__ __launch_bounds__(256) void k_upd1(const float* __restrict__ h,
        const float* __restrict__ agg,
        const unsigned short* __restrict__ wh, const unsigned short* __restrict__ wl,
        const float* __restrict__ b1, float* __restrict__ tv, int nNodes) {
    const int lane = threadIdx.x & 63;
    const int wib  = threadIdx.x >> 6;
    const int quad = lane >> 4, col = lane & 15;
    __shared__ unsigned short sm[4][16 * 136];
    unsigned short* __restrict__ mt = sm[wib];

    short8 bh[4][4], bl[4][4];
#pragma unroll
    for (int nt = 0; nt < 4; ++nt)
#pragma unroll
        for (int kf = 0; kf < 4; ++kf) {
            LOADFRAG(bh[nt][kf], wh, nt, 4, kf);
            LOADFRAG(bl[nt][kf], wl, nt, 4, kf);
        }
    float bv[4];
#pragma unroll
    for (int nt = 0; nt < 4; ++nt) bv[nt] = b1[nt * 16 + col];

    const int nTiles = (nNodes + 15) >> 4;
    const int wid = blockIdx.x * 4 + wib;
    const int nw  = gridDim.x * 4;
    for (int tile = wid; tile < nTiles; tile += nw) {
        const int base = tile * 16;
#pragma unroll
        for (int j = 0; j < 16; ++j) {
            int row = min(base + j, nNodes - 1);
            mt[j * 136 + lane]      = f2bf(h[(size_t)row * 64 + lane]);
            mt[j * 136 + 64 + lane] = f2bf(agg[(size_t)row * 64 + lane]);
        }
        __builtin_amdgcn_s_waitcnt(0);
        short8 a[4];
#pragma unroll
        for (int kf = 0; kf < 4; ++kf)
            a[kf] = *(const short8*)&mt[col * 136 + kf * 32 + quad * 8];
#pragma unroll
        for (int nt = 0; nt < 4; ++nt) {
            float4v c = {0.f, 0.f, 0.f, 0.f};
#pragma unroll
            for (int kf = 0; kf < 4; ++kf) c = MFMA16(a[kf], bh[nt][kf], c);
#pragma unroll
            for (int kf = 0; kf < 4; ++kf) c = MFMA16(a[kf], bl[nt][kf], c);
#pragma unroll
            for (int r = 0; r < 4; ++r) {
                int row = base + quad * 4 + r;
                if (row < nNodes)
                    tv[(size_t)row * 64 + nt * 16 + col] = fmaxf(c[r] + bv[nt], 0.f);
            }
        }
    }
}

// h += relu(tv @ U2 + b2); zero tv(=agg) for next layer; optional colsum
__global__ __launch_bounds__(256) void k_upd2(float* __restrict__ h,
        float* __restrict__ tv,
        const unsigned short* __restrict__ wh, const unsigned short* __restrict__ wl,
        const float* __restrict__ b2, float* __restrict__ colsum,
        int nNodes, int doCS) {
    const int lane = threadIdx.x & 63;
    const int wib  = threadIdx.x >> 6;
    const int quad = lane >> 4, col = lane & 15;
    __shared__ unsigned short sm[4][16 * 72];
    unsigned short* __restrict__ mt = sm[wib];

    short8 bh[4][2], bl[4][2];
#pragma unroll
    for (int nt = 0; nt < 4; ++nt)
#pragma unroll
        for (int kf = 0; kf < 2; ++kf) {
            LOADFRAG(bh[nt][kf], wh, nt, 2, kf);
            LOADFRAG(bl[nt][kf], wl, nt, 2, kf);
        }
    float bv[4];
#pragma unroll
    for (int nt = 0; nt < 4; ++nt) bv[nt] = b2[nt * 16 + col];

    float cs0 = 0.f, cs1 = 0.f, cs2 = 0.f, cs3 = 0.f;
    const int nTiles = (nNodes + 15) >> 4;
    const int wid = blockIdx.x * 4 + wib;
    const int nw  = gridDim.x * 4;
    for (int tile = wid; tile < nTiles; tile += nw) {
        const int base = tile * 16;
#pragma unroll
        for (int j = 0; j < 16; ++j) {
            int row = min(base + j, nNodes - 1);
            mt[j * 72 + lane] = f2bf(tv[(size_t)row * 64 + lane]);
        }
        __builtin_amdgcn_s_waitcnt(0);   // drains vmcnt too -> safe to zero tv
#pragma unroll
        for (int j = 0; j < 16; ++j) {
            int row = base + j;
            if (row < nNodes) tv[(size_t)row * 64 + lane] = 0.f;
        }
        short8 a0 = *(const short8*)&mt[col * 72 + quad * 8];
        short8 a1 = *(const short8*)&mt[col * 72 + 32 + quad * 8];
#pragma unroll
        for (int nt = 0; nt < 4; ++nt) {
            float4v c = {0.f, 0.f, 0.f, 0.f};
            c = MFMA16(a0, bh[nt][0], c);
            c = MFMA16(a1, bh[nt][1], c);
            c = MFMA16(a0, bl[nt][0], c);
            c = MFMA16(a1, bl[nt][1], c);
#pragma unroll
            for (int r = 0; r < 4; ++r) {
                int row = base + quad * 4 + r;
                if (row < nNodes) {
                    float* hp = &h[(size_t)row * 64 + nt * 16 + col];
                    float hn = *hp + fmaxf(c[r] + bv[nt], 0.f);
                    *hp = hn;
                    cs0 += (nt == 0) ? hn : 0.f;
                    cs1 += (nt == 1) ? hn : 0.f;
                    cs2 += (nt == 2) ? hn : 0.f;
                    cs3 += (nt == 3) ? hn : 0.f;
                }
            }
        }
    }
    if (doCS) {
        cs0 += __shfl_xor(cs0, 16); cs0 += __shfl_xor(cs0, 32);
        cs1 += __shfl_xor(cs1, 16); cs1 += __shfl_xor(cs1, 32);
        cs2 += __shfl_xor(cs2, 16); cs2 += __shfl_xor(cs2, 32);
        cs3 += __shfl_xor(cs3, 16); cs3 += __shfl_xor(cs3, 32);
        const float tot = (quad == 0) ? cs0 : (quad == 1) ? cs1
                        : (quad == 2) ? cs2 : cs3;
        atomicAdd(&colsum[lane], tot);   // lane == quad*16+col
    }
}

// ---------------- edge kernel: contiguous-chunk 32-edge batches ----------------
#define EST 72   // ushorts per staged row

__global__ __launch_bounds__(256) void k_edge(const unsigned short* __restrict__ P,
        const unsigned short* __restrict__ Q, const float* __restrict__ ea_s,
        const int* __restrict__ col_src, const int* __restrict__ dst_s,
        const float* __restrict__ w1e,
        const unsigned short* __restrict__ wh, const unsigned short* __restrict__ wl,
        const float* __restrict__ b2,
        float* __restrict__ agg, int nEdges) {
    const int lane = threadIdx.x & 63;
    const int wib  = threadIdx.x >> 6;
    const int wid  = blockIdx.x * 4 + wib;
    const int nw   = gridDim.x * 4;
    const int quad = lane >> 4;
    const int col  = lane & 15;
    const int li   = lane & 31;

    __shared__ unsigned short m1b[4][32 * EST];
    unsigned short* __restrict__ mt = m1b[wib];

    float w1ec[6];
#pragma unroll
    for (int j = 0; j < 6; ++j) w1ec[j] = w1e[j * 64 + lane];

    short8 bhi[4][2], blo[4][2];
#pragma unroll
    for (int nt = 0; nt < 4; ++nt)
#pragma unroll
        for (int kf = 0; kf < 2; ++kf) {
            LOADFRAG(bhi[nt][kf], wh, nt, 2, kf);
            LOADFRAG(blo[nt][kf], wl, nt, 2, kf);
        }
    float b2v[4];
#pragma unroll
    for (int nt = 0; nt < 4; ++nt) b2v[nt] = b2[nt * 16 + col];

    // contiguous chunk per wave: dst-sorted CSR -> P/agg locality
    const int nBatch = (nEdges + 31) >> 5;
    const int per = nBatch / nw, rem = nBatch % nw;
    const int btLo = wid * per + min(wid, rem);
    const int btHi = btLo + per + (wid < rem ? 1 : 0);

    for (int bt = btLo; bt < btHi; ++bt) {
        const int base = __builtin_amdgcn_readfirstlane(bt << 5);
        const int gidx = min(base + li, nEdges - 1);
        const int vdj = dst_s[gidx];          // row li's dst (lanes 32-63 dup)
        const int vsj = col_src[gidx];        // row li's src
        const int vprev = __shfl_up(vdj, 1);
        unsigned long long bmask =
            __ballot(lane < 32 && (li == 0 || vdj != vprev));
        bmask |= (1ull << 32) | 1ull;

        // ---- stage 32 rows: m1 -> bf16 -> LDS (straight-line, b1 in P) ----
#pragma unroll
        for (int j = 0; j < 32; ++j) {
            const int d = __builtin_amdgcn_readlane(vdj, j);
            const int s = __builtin_amdgcn_readlane(vsj, j);
            const int idx = min(base + j, nEdges - 1);   // uniform
            float t = bf2f(P[(size_t)d * 64 + lane]) +
                      bf2f(Q[(size_t)s * 64 + lane]);
            const float* eap = ea_s + (size_t)idx * 6;
#pragma unroll
            for (int jj = 0; jj < 6; ++jj) t = fmaf(eap[jj], w1ec[jj], t);
            mt[j * EST + lane] = f2bf(fmaxf(t, 0.f));
        }
        __builtin_amdgcn_s_waitcnt(0);   // wave-local LDS drain

        short8 a00 = *(const short8*)&mt[col * EST + quad * 8];
        short8 a01 = *(const short8*)&mt[col * EST + 32 + quad * 8];
        short8 a10 = *(const short8*)&mt[(16 + col) * EST + quad * 8];
        short8 a11 = *(const short8*)&mt[(16 + col) * EST + 32 + quad * 8];

        // m2 for both 16-row tiles, masked+relu'd up front
        float4v m2v[2][4];
#pragma unroll
        for (int nt = 0; nt < 4; ++nt) {
            float4v c0 = {0.f, 0.f, 0.f, 0.f};
            float4v c1 = {0.f, 0.f, 0.f, 0.f};
            c0 = MFMA16(a00, bhi[nt][0], c0);
            c0 = MFMA16(a01, bhi[nt][1], c0);
            c0 = MFMA16(a00, blo[nt][0], c0);
            c0 = MFMA16(a01, blo[nt][1], c0);
            c1 = MFMA16(a10, bhi[nt][0], c1);
            c1 = MFMA16(a11, bhi[nt][1], c1);
            c1 = MFMA16(a10, blo[nt][0], c1);
            c1 = MFMA16(a11, blo[nt][1], c1);
#pragma unroll
            for (int r = 0; r < 4; ++r) {
                const bool v0 = base + (quad * 4 + r) < nEdges;
                const bool v1 = base + 16 + (quad * 4 + r) < nEdges;
                m2v[0][nt][r] = v0 ? fmaxf(c0[r] + b2v[nt], 0.f) : 0.f;
                m2v[1][nt][r] = v1 ? fmaxf(c1[r] + b2v[nt], 0.f) : 0.f;
            }
        }

        // ---- segmented reduce + one coalesced atomic per segment ----
        int r0 = 0;
        while (r0 < 32) {
            const int nid = __builtin_amdgcn_readlane(vdj, r0);
            const int r1 = r0 + 1 + (int)__builtin_ctzll(bmask >> (r0 + 1));
            float s0 = 0.f, s1 = 0.f, s2 = 0.f, s3 = 0.f;
#pragma unroll
            for (int t = 0; t < 2; ++t)
#pragma unroll
                for (int r = 0; r < 4; ++r) {
                    const int R = t * 16 + quad * 4 + r;
                    const bool in = (R >= r0) && (R < r1);
                    s0 += in ? m2v[t][0][r] : 0.f;
                    s1 += in ? m2v[t][1][r] : 0.f;
                    s2 += in ? m2v[t][2][r] : 0.f;
                    s3 += in ? m2v[t][3][r] : 0.f;
                }
            s0 += __shfl_xor(s0, 16); s0 += __shfl_xor(s0, 32);
            s1 += __shfl_xor(s1, 16); s1 += __shfl_xor(s1, 32);
            s2 += __shfl_xor(s2, 16); s2 += __shfl_xor(s2, 32);
            s3 += __shfl_xor(s3, 16); s3 += __shfl_xor(s3, 32);
            const float tot = (quad == 0) ? s0 : (quad == 1) ? s1
                            : (quad == 2) ? s2 : s3;
            atomicAdd(&agg[(size_t)nid * 64 + lane], tot);
            r0 = r1;
        }
    }
}

__global__ void k_out(const float* __restrict__ colsum, const float* __restrict__ pw,
                      const float* __restrict__ pb, float* __restrict__ out, int nNodes) {
    const int lane = threadIdx.x;
    float v = colsum[lane] * pw[lane];
#pragma unroll
    for (int off = 32; off; off >>= 1) v += __shfl_down(v, off);
    if (lane == 0) out[0] = v + (float)nNodes * pb[0];
}

extern "C" void kernel_launch(void* const* d_in, const int* in_sizes, int n_in,
                              void* d_out, int out_size, void* d_ws, size_t ws_size,
                              hipStream_t stream) {
    const float* x     = (const float*)d_in[0];
    const int*   ei    = (const int*)d_in[1];
    const float* ea    = (const float*)d_in[2];
    const float* lin_w = (const float*)d_in[3];
    const float* lin_b = (const float*)d_in[4];
    const float* mw1   = (const float*)d_in[5];
    const float* mb1   = (const float*)d_in[6];
    const float* mw2   = (const float*)d_in[7];
    const float* mb2   = (const float*)d_in[8];
    const float* uw1   = (const float*)d_in[9];
    const float* ub1   = (const float*)d_in[10];
    const float* uw2   = (const float*)d_in[11];
    const float* ub2   = (const float*)d_in[12];
    const float* pw    = (const float*)d_in[13];
    const float* pb    = (const float*)d_in[14];

    const int nNodes = in_sizes[0] / 128;
    const int nEdges = in_sizes[1] / 2;
    const int* src = ei;            // edge_index[0]
    const int* dst = ei + nEdges;   // edge_index[1]

    // workspace layout (floats, then ushorts, then ints)
    float* h       = (float*)d_ws;
    float* agg     = h   + (size_t)nNodes * 64;   // also tv (in-place upd1)
    float* ea_s    = agg + (size_t)nNodes * 64;
    float* colsum  = ea_s + (size_t)nEdges * 6;
    unsigned short* Pb  = (unsigned short*)(colsum + 64);
    unsigned short* Qb  = Pb + (size_t)nNodes * 64;
    unsigned short* wpH = Qb + (size_t)nNodes * 64;
    unsigned short* wpL = wpH + WP_TOTAL;
    int*   deg     = (int*)(wpL + WP_TOTAL);
    int*   cursor  = deg + nNodes;
    int*   local   = cursor + nNodes;
    int*   bsum    = local + nNodes;
    int*   col_src = bsum + 256;
    int*   dst_s   = col_src + nEdges;

    const int NB_T    = 392;                     // node-GEMM tiles: ~2/wave
    const int NB_EDGE = 2048;
    const int NB_FLAT = (nEdges + 255) / 256;
    const int NB_SCAN = (nNodes + 255) / 256;

    // ---- one-time: CSR build + weight prep ----
    hipMemsetAsync(deg, 0, (size_t)nNodes * sizeof(int), stream);
    hipMemsetAsync(colsum, 0, 64 * sizeof(float), stream);
    hipMemsetAsync(agg, 0, (size_t)nNodes * 64 * sizeof(float), stream);
    k_hist<<<NB_FLAT, 256, 0, stream>>>(dst, deg, nEdges);
    k_scan1<<<NB_SCAN, 256, 0, stream>>>(deg, local, bsum, nNodes);
    k_scan2<<<1, 256, 0, stream>>>(bsum, NB_SCAN);
    k_scan3<<<NB_SCAN, 256, 0, stream>>>(local, bsum, cursor, nNodes);
    k_scatter<<<NB_FLAT, 256, 0, stream>>>(src, dst, ea, cursor, col_src, dst_s, ea_s, nEdges);
    k_wprep<<<(WP_TOTAL + 255) / 256, 256, 0, stream>>>(lin_w, mw1, mw2, uw1, uw2, wpH, wpL);

    k_in<<<NB_T, 256, 0, stream>>>(x, wpH + OFF_IN, wpL + OFF_IN, lin_b, h, nNodes);

    for (int l = 0; l < 4; ++l) {
        k_pre<<<NB_T, 256, 0, stream>>>(h, wpH + OFF_PRE(l), wpL + OFF_PRE(l),
            mb1 + l * 64, Pb, Qb, nNodes);
        k_edge<<<NB_EDGE, 256, 0, stream>>>(Pb, Qb, ea_s, col_src, dst_s,
            mw1 + (size_t)l * 134 * 64 + 128 * 64,
            wpH + OFF_MW2(l), wpL + OFF_MW2(l), mb2 + l * 64, agg, nEdges);
        k_upd1<<<NB_T, 256, 0, stream>>>(h, agg,
            wpH + OFF_UW1(l), wpL + OFF_UW1(l), ub1 + l * 64, agg, nNodes);
        k_upd2<<<NB_T, 256, 0, stream>>>(h, agg,
            wpH + OFF_UW2(l), wpL + OFF_UW2(l), ub2 + l * 64,
            colsum, nNodes, (l == 3) ? 1 : 0);
    }

    k_out<<<1, 64, 0, stream>>>(colsum, pw, pb, (float*)d_out, nNodes);
}